// Round 12
// baseline (383.630 us; speedup 1.0000x reference)
//
#include <hip/hip_runtime.h>

#define N_NODES 100000
#define N_EDGES 625000
#define HIDDEN 128
#define NUM_GRAPHS 512
#define CAP 40       // max in-degree capacity; Poisson(6.25) => P(deg>40) ~ e-43
#define PADN 100096  // multiple of 256; 3128 gather-chunks of 32

typedef unsigned int uint;
typedef unsigned short ushort;
typedef short v8s __attribute__((ext_vector_type(8)));
typedef float v16f __attribute__((ext_vector_type(16)));

__device__ __forceinline__ float b2f_lo(uint u) { return __uint_as_float(u << 16); }
__device__ __forceinline__ float b2f_hi(uint u) { return __uint_as_float(u & 0xffff0000u); }
__device__ __forceinline__ uint f2b(float f) {  // RNE f32 -> bf16 bits
  uint u = __float_as_uint(f);
  return (u + 0x7fffu + ((u >> 16) & 1u)) >> 16;
}
__device__ __forceinline__ float rbf(float f) {  // round-to-bf16 as float (== b2f(f2b(f)))
  return __uint_as_float(f2b(f) << 16);
}

// ---------------- weight quantize -> FRAGMENT-ORDERED bf16 ----------------
__global__ __launch_bounds__(256) void wtrans_k(const float* __restrict__ W1,
                                                const float* __restrict__ W2,
                                                ushort* __restrict__ Wt) {
  int mat = blockIdx.x;                       // 0..7 = layer*2 + which
  const float* W = ((mat & 1) ? W2 : W1) + (size_t)(mat >> 1) * 16384;
  ushort* o = Wt + (size_t)mat * 16384;
#pragma unroll
  for (int j = 0; j < 64; j++) {
    int idx = threadIdx.x + 256 * j;          // coalesced read W[k][n]
    int k = idx >> 7, n = idx & 127;
    int c = n >> 5, l31 = n & 31;
    int ks = k >> 4, khalf = (k >> 3) & 1, e = k & 7;
    o[(((c * 8 + ks) << 6) + (khalf << 5) + l31) * 8 + e] = (ushort)f2b(W[idx]);
  }
}

// ---------------- build dst-keyed adjacency (per call) ----------------
__global__ __launch_bounds__(256) void build_k(const int* __restrict__ src,
                                               const int* __restrict__ dst,
                                               int* __restrict__ cursor,
                                               int* __restrict__ slots) {
  int e = blockIdx.x * 256 + threadIdx.x;
  if (e >= N_EDGES) return;
  int d = dst[e];
  int p = atomicAdd(&cursor[d], 1);
  if (p < CAP) slots[(size_t)d * CAP + p] = src[e];
}

// ---------------- degree-grouped permutation, two-level (LDS-aggregated) ----------------
__global__ __launch_bounds__(256) void hist_k(const int* __restrict__ cursor,
                                              int* __restrict__ bins) {
  __shared__ int lb[CAP + 1];
  int tid = threadIdx.x;
  if (tid <= CAP) lb[tid] = 0;
  __syncthreads();
  int n = blockIdx.x * 256 + tid;
  if (n < N_NODES) {
    int d = cursor[n]; if (d > CAP) d = CAP;
    atomicAdd(&lb[d], 1);                     // LDS atomic: cheap
  }
  __syncthreads();
  if (tid <= CAP && lb[tid] > 0) atomicAdd(&bins[tid], lb[tid]);  // fire-and-forget
}

__global__ __launch_bounds__(64) void scan_k(int* __restrict__ bins) {
  int i = threadIdx.x;
  int c = (i <= CAP) ? bins[i] : 0;
  int incl = c;
#pragma unroll
  for (int off = 1; off < 64; off <<= 1) {
    int t = __shfl_up(incl, off, 64);
    if (i >= off) incl += t;
  }
  if (i <= CAP) bins[i] = incl - c;           // exclusive prefix
}

// LPT dispatch: perm REVERSED (descending degree) so deg-40 blocks launch first.
__global__ __launch_bounds__(256) void scatter_k(const int* __restrict__ cursor,
                                                 int* __restrict__ bins,
                                                 int* __restrict__ perm) {
  __shared__ int lb[CAP + 1];
  __shared__ int lbase[CAP + 1];
  int tid = threadIdx.x;
  if (tid <= CAP) lb[tid] = 0;
  __syncthreads();
  int n = blockIdx.x * 256 + tid;
  int d = 0, rank = 0;
  bool real = (n < N_NODES);
  if (real) {
    d = cursor[n]; if (d > CAP) d = CAP;
    rank = atomicAdd(&lb[d], 1);
  }
  __syncthreads();
  if (tid <= CAP) {
    int c = lb[tid];
    lbase[tid] = c > 0 ? atomicAdd(&bins[tid], c) : 0;
  }
  __syncthreads();
  if (real) perm[(N_NODES - 1) - (lbase[d] + rank)] = n;   // descending degree
  else if (n < PADN) perm[n] = 0;
}

// ================= shared GEMM tail (flip-GEMM1 + shfl z + GEMM2) =================
union U { uint4 u; v8s s; };

__device__ __forceinline__ void gemm_tail(const U afr[8],
                                          const ushort* __restrict__ W1f,
                                          const ushort* __restrict__ W2f,
                                          const float* __restrict__ b1,
                                          const float* __restrict__ b2,
                                          ushort* __restrict__ hout,
                                          int lane, int l31, int khalf,
                                          int tb, int prow) {
  // ---- GEMM1 (flipped): z^T = W1^T-as-A @ agg-as-B; lane = node row ----
  const uint4* W1v = (const uint4*)W1f;       // frag-ordered: slot*64 + lane
  v16f acc1[4] = {};
#pragma unroll
  for (int c = 0; c < 4; c++)
#pragma unroll
    for (int ks = 0; ks < 8; ks++) {
      U b; b.u = W1v[((c * 8 + ks) << 6) + lane];
      acc1[c] = __builtin_amdgcn_mfma_f32_32x32x16_bf16(b.s, afr[ks].s, acc1[c], 0, 0, 0);
    }

  // bias + relu + pack: lane holds z[r=l31][k'], k' = 32c + (reg&3) + 8*(reg>>2) + 4*khalf
  uint u[4][4][2];
#pragma unroll
  for (int c = 0; c < 4; c++)
#pragma unroll
    for (int b = 0; b < 4; b++)
#pragma unroll
      for (int ap = 0; ap < 2; ap++) {
        int r0 = 2 * ap + 4 * b, r1 = r0 + 1;
        float v0 = fmaxf(acc1[c][r0] + b1[c * 32 + 2 * ap + 8 * b + 4 * khalf], 0.f);
        float v1 = fmaxf(acc1[c][r1] + b1[c * 32 + 2 * ap + 1 + 8 * b + 4 * khalf], 0.f);
        u[c][b][ap] = f2b(v0) | (f2b(v1) << 16);
      }

  uint got[4][2][2];
#pragma unroll
  for (int c = 0; c < 4; c++)
#pragma unroll
    for (int bh = 0; bh < 2; bh++)
#pragma unroll
      for (int ap = 0; ap < 2; ap++) {
        uint send = khalf ? u[c][2 * bh][ap] : u[c][2 * bh + 1][ap];
        got[c][bh][ap] = __shfl_xor(send, 32, 64);
      }

  U az[8];
#pragma unroll
  for (int ks = 0; ks < 8; ks++) {
    uint o0 = khalf ? u[ks >> 1][2 * (ks & 1) + 1][0] : u[ks >> 1][2 * (ks & 1)][0];
    uint o1 = khalf ? u[ks >> 1][2 * (ks & 1) + 1][1] : u[ks >> 1][2 * (ks & 1)][1];
    uint g0 = got[ks >> 1][ks & 1][0];
    uint g1 = got[ks >> 1][ks & 1][1];
    az[ks].u.x = khalf ? g0 : o0;
    az[ks].u.y = khalf ? g1 : o1;
    az[ks].u.z = khalf ? o0 : g0;
    az[ks].u.w = khalf ? o1 : g1;
  }

  // ---- GEMM2 (normal): h_out = z @ W2 + b2 ----
  const uint4* W2v = (const uint4*)W2f;
  v16f acc2[4] = {};
#pragma unroll
  for (int c = 0; c < 4; c++)
#pragma unroll
    for (int ks = 0; ks < 8; ks++) {
      U b; b.u = W2v[((c * 8 + ks) << 6) + lane];
      acc2[c] = __builtin_amdgcn_mfma_f32_32x32x16_bf16(az[ks].s, b.s, acc2[c], 0, 0, 0);
    }

  int trow[16];
#pragma unroll
  for (int r = 0; r < 16; r++) {
    int m = (r & 3) + 8 * (r >> 2) + 4 * khalf;
    trow[r] = __shfl(prow, m, 64);
  }
  float bv2[4];
#pragma unroll
  for (int c = 0; c < 4; c++) bv2[c] = b2[c * 32 + l31];
#pragma unroll
  for (int c = 0; c < 4; c++) {
    int col = c * 32 + l31;
#pragma unroll
    for (int r = 0; r < 16; r++) {
      int m = (r & 3) + 8 * (r >> 2) + 4 * khalf;
      if (tb + m < N_NODES)
        hout[(size_t)trow[r] * HIDDEN + col] = (ushort)f2b(acc2[c][r] + bv2[c]);
    }
  }
}

// ---------------- fused layer (layers 2..4): bf16 h input, depth-3 gather ----------------
__device__ __forceinline__ void loadrow(uint4 dst[8], const uint4* __restrict__ rowp,
                                        int khalf) {
#pragma unroll
  for (int ks = 0; ks < 8; ks++) dst[ks] = rowp[khalf + 2 * ks];
}

__device__ __forceinline__ void accum8(const uint4 u[8], float acc[8][8]) {
#pragma unroll
  for (int ks = 0; ks < 8; ks++) {
    acc[ks][0] += b2f_lo(u[ks].x); acc[ks][1] += b2f_hi(u[ks].x);
    acc[ks][2] += b2f_lo(u[ks].y); acc[ks][3] += b2f_hi(u[ks].y);
    acc[ks][4] += b2f_lo(u[ks].z); acc[ks][5] += b2f_hi(u[ks].z);
    acc[ks][6] += b2f_lo(u[ks].w); acc[ks][7] += b2f_hi(u[ks].w);
  }
}

__global__ __launch_bounds__(64, 2) void layer_k(const ushort* __restrict__ hin,
                                                 const int* __restrict__ cursor,
                                                 const int* __restrict__ slots,
                                                 const int* __restrict__ perm,
                                                 const ushort* __restrict__ W1f,
                                                 const ushort* __restrict__ W2f,
                                                 const float* __restrict__ b1,
                                                 const float* __restrict__ b2,
                                                 ushort* __restrict__ hout) {
  int lane = threadIdx.x;
  int l31 = lane & 31;
  int khalf = lane >> 5;
  int tb = blockIdx.x * 32;
  int prow = perm[tb + l31];
  bool valid = (tb + l31) < N_NODES;

  float acc[8][8];
#pragma unroll
  for (int ks = 0; ks < 8; ks++)
#pragma unroll
    for (int e = 0; e < 8; e++) acc[ks][e] = 0.f;

  const uint4* base = (const uint4*)hin;
  uint4 A[8], B[8], C[8];
  loadrow(A, base + (size_t)prow * 16, khalf);          // self

  int deg = valid ? cursor[prow] : 0;
  if (deg > CAP) deg = CAP;
  const int* sl = slots + (size_t)prow * CAP;
  if (deg > 0) loadrow(B, base + (size_t)sl[0] * 16, khalf);   // n0
  if (deg > 1) loadrow(C, base + (size_t)sl[1] * 16, khalf);   // n1
  int sA = (deg > 2) ? sl[2] : 0;
  __builtin_amdgcn_sched_barrier(0);
  accum8(A, acc);                                       // self

  int j = 0;
  while (j + 3 <= deg) {
    loadrow(A, base + (size_t)sA * 16, khalf);          // n(j+2)
    int sB = (j + 3 < deg) ? sl[j + 3] : 0;
    __builtin_amdgcn_sched_barrier(0);
    accum8(B, acc);                                     // n(j)
    loadrow(B, base + (size_t)sB * 16, khalf);          // n(j+3)
    int sC = (j + 4 < deg) ? sl[j + 4] : 0;
    __builtin_amdgcn_sched_barrier(0);
    accum8(C, acc);                                     // n(j+1)
    loadrow(C, base + (size_t)sC * 16, khalf);          // n(j+4)
    sA = (j + 5 < deg) ? sl[j + 5] : 0;
    __builtin_amdgcn_sched_barrier(0);
    accum8(A, acc);                                     // n(j+2)
    j += 3;
  }
  if (j < deg) accum8(B, acc);                          // n(j)
  if (j + 1 < deg) accum8(C, acc);                      // n(j+1)

  U afr[8];
#pragma unroll
  for (int ks = 0; ks < 8; ks++) {
    afr[ks].u.x = f2b(acc[ks][0]) | (f2b(acc[ks][1]) << 16);
    afr[ks].u.y = f2b(acc[ks][2]) | (f2b(acc[ks][3]) << 16);
    afr[ks].u.z = f2b(acc[ks][4]) | (f2b(acc[ks][5]) << 16);
    afr[ks].u.w = f2b(acc[ks][6]) | (f2b(acc[ks][7]) << 16);
  }

  gemm_tail(afr, W1f, W2f, b1, b2, hout, lane, l31, khalf, tb, prow);
}

// ---------------- fused FIRST layer: gather straight from node_emb[x[.]] ----------------
// emb table = 14 KB f32 (L1-resident), x = 400 KB (L2-hot): layer-1's gather
// traffic collapses from ~186 MB (L3) to cache-resident. rbf() at accumulate
// reproduces embed_k's bf16 rounding bit-identically. Depth-2 pipeline.
__device__ __forceinline__ void loadrow_emb(float4 dst[16], const float* __restrict__ row,
                                            int khalf) {
  const float4* rp = (const float4*)row;
#pragma unroll
  for (int ks = 0; ks < 8; ks++) {
    dst[2 * ks]     = rp[4 * ks + 2 * khalf];
    dst[2 * ks + 1] = rp[4 * ks + 2 * khalf + 1];
  }
}

__device__ __forceinline__ void accum_emb(const float4 u[16], float acc[8][8]) {
#pragma unroll
  for (int ks = 0; ks < 8; ks++) {
    acc[ks][0] += rbf(u[2 * ks].x);     acc[ks][1] += rbf(u[2 * ks].y);
    acc[ks][2] += rbf(u[2 * ks].z);     acc[ks][3] += rbf(u[2 * ks].w);
    acc[ks][4] += rbf(u[2 * ks + 1].x); acc[ks][5] += rbf(u[2 * ks + 1].y);
    acc[ks][6] += rbf(u[2 * ks + 1].z); acc[ks][7] += rbf(u[2 * ks + 1].w);
  }
}

__global__ __launch_bounds__(64, 2) void layer1_k(const int* __restrict__ x,
                                                  const float* __restrict__ emb,
                                                  const int* __restrict__ cursor,
                                                  const int* __restrict__ slots,
                                                  const int* __restrict__ perm,
                                                  const ushort* __restrict__ W1f,
                                                  const ushort* __restrict__ W2f,
                                                  const float* __restrict__ b1,
                                                  const float* __restrict__ b2,
                                                  ushort* __restrict__ hout) {
  int lane = threadIdx.x;
  int l31 = lane & 31;
  int khalf = lane >> 5;
  int tb = blockIdx.x * 32;
  int prow = perm[tb + l31];
  bool valid = (tb + l31) < N_NODES;

  float acc[8][8];
#pragma unroll
  for (int ks = 0; ks < 8; ks++)
#pragma unroll
    for (int e = 0; e < 8; e++) acc[ks][e] = 0.f;

  float4 A[16], B[16];
  loadrow_emb(A, emb + (size_t)x[prow] * HIDDEN, khalf);       // self

  int deg = valid ? cursor[prow] : 0;
  if (deg > CAP) deg = CAP;
  const int* sl = slots + (size_t)prow * CAP;
  if (deg > 0) loadrow_emb(B, emb + (size_t)x[sl[0]] * HIDDEN, khalf);  // n0
  __builtin_amdgcn_sched_barrier(0);
  accum_emb(A, acc);                                    // self

  int j = 0;
  while (j + 2 <= deg) {
    loadrow_emb(A, emb + (size_t)x[sl[j + 1]] * HIDDEN, khalf);
    __builtin_amdgcn_sched_barrier(0);
    accum_emb(B, acc);                                  // n(j)
    if (j + 2 < deg) loadrow_emb(B, emb + (size_t)x[sl[j + 2]] * HIDDEN, khalf);
    __builtin_amdgcn_sched_barrier(0);
    accum_emb(A, acc);                                  // n(j+1)
    j += 2;
  }
  if (j < deg) accum_emb(B, acc);                       // last odd neighbor

  U afr[8];
#pragma unroll
  for (int ks = 0; ks < 8; ks++) {
    afr[ks].u.x = f2b(acc[ks][0]) | (f2b(acc[ks][1]) << 16);
    afr[ks].u.y = f2b(acc[ks][2]) | (f2b(acc[ks][3]) << 16);
    afr[ks].u.z = f2b(acc[ks][4]) | (f2b(acc[ks][5]) << 16);
    afr[ks].u.w = f2b(acc[ks][6]) | (f2b(acc[ks][7]) << 16);
  }

  gemm_tail(afr, W1f, W2f, b1, b2, hout, lane, l31, khalf, tb, prow);
}

// ---------------- fused pool+MLP: g = segsum(h); out = mlp(g) ----------------
__global__ __launch_bounds__(256) void poolmlp_k(const ushort* __restrict__ h,
                                                 const int* __restrict__ batch,
                                                 const float* __restrict__ W1, const float* __restrict__ b1,
                                                 const float* __restrict__ W2, const float* __restrict__ b2,
                                                 const float* __restrict__ W3, const float* __restrict__ b3,
                                                 float* __restrict__ out) {
  __shared__ int se[2];
  __shared__ float red[16][16][8];
  __shared__ float gl[128];
  __shared__ float r2[64];
  __shared__ float r3[32];
  int gi = blockIdx.x, tid = threadIdx.x;
  if (tid < 2) {
    int target = gi + tid;
    int lo = 0, hi = N_NODES;
    while (lo < hi) {
      int mid = (lo + hi) >> 1;
      if (batch[mid] < target) lo = mid + 1; else hi = mid;
    }
    se[tid] = lo;
  }
  __syncthreads();
  int start = se[0], end = se[1];
  int cg = tid & 15, rg = tid >> 4;
  float acc[8] = {0.f, 0.f, 0.f, 0.f, 0.f, 0.f, 0.f, 0.f};
  for (int r = start + rg; r < end; r += 16) {
    uint4 v = ((const uint4*)h)[r * 16 + cg];
    acc[0] += b2f_lo(v.x); acc[1] += b2f_hi(v.x);
    acc[2] += b2f_lo(v.y); acc[3] += b2f_hi(v.y);
    acc[4] += b2f_lo(v.z); acc[5] += b2f_hi(v.z);
    acc[6] += b2f_lo(v.w); acc[7] += b2f_hi(v.w);
  }
#pragma unroll
  for (int j = 0; j < 8; j++) red[rg][cg][j] = acc[j];
  __syncthreads();
  if (rg == 0) {
    float s[8];
#pragma unroll
    for (int j = 0; j < 8; j++) s[j] = red[0][cg][j];
#pragma unroll
    for (int i = 1; i < 16; i++)
#pragma unroll
      for (int j = 0; j < 8; j++) s[j] += red[i][cg][j];
#pragma unroll
    for (int j = 0; j < 8; j++) gl[cg * 8 + j] = s[j];
  }
  __syncthreads();
  if (tid < 64) {
    float s = b1[tid];
    for (int k = 0; k < 128; k++) s = fmaf(gl[k], W1[k * 64 + tid], s);
    r2[tid] = fmaxf(s, 0.f);
  }
  __syncthreads();
  if (tid < 32) {
    float s2 = b2[tid];
    for (int k = 0; k < 64; k++) s2 = fmaf(r2[k], W2[k * 32 + tid], s2);
    r3[tid] = fmaxf(s2, 0.f);
  }
  __syncthreads();
  if (tid < 64) {
    float pv = (tid < 32) ? r3[tid] * W3[tid] : 0.f;
#pragma unroll
    for (int off = 32; off > 0; off >>= 1) pv += __shfl_down(pv, off);
    if (tid == 0) out[gi] = pv + b3[0];
  }
}

extern "C" void kernel_launch(void* const* d_in, const int* in_sizes, int n_in,
                              void* d_out, int out_size, void* d_ws, size_t ws_size,
                              hipStream_t stream) {
  const int* x = (const int*)d_in[0];
  const int* src = (const int*)d_in[1];
  const int* dst = src + N_EDGES;
  const int* batch = (const int*)d_in[3];
  const float* node_emb = (const float*)d_in[4];
  const float* cW1 = (const float*)d_in[6];
  const float* cb1 = (const float*)d_in[7];
  const float* cW2 = (const float*)d_in[8];
  const float* cb2 = (const float*)d_in[9];
  const float* mW1 = (const float*)d_in[10];
  const float* mb1 = (const float*)d_in[11];
  const float* mW2 = (const float*)d_in[12];
  const float* mb2 = (const float*)d_in[13];
  const float* mW3 = (const float*)d_in[14];
  const float* mb3 = (const float*)d_in[15];
  float* out = (float*)d_out;

  char* p = (char*)d_ws;
  const size_t HB = (size_t)N_NODES * HIDDEN * sizeof(ushort);  // 25.6 MB
  ushort* h = (ushort*)p;      p += HB;
  ushort* t0 = (ushort*)p;     p += HB;
  ushort* Wtb = (ushort*)p;    p += (size_t)8 * 16384 * sizeof(ushort);
  int* cursor = (int*)p;       p += (size_t)N_NODES * sizeof(int);
  int* bins = (int*)p;         p += 64 * sizeof(int);
  int* slots = (int*)p;        p += (size_t)N_NODES * CAP * sizeof(int);
  int* perm = (int*)p;         p += (size_t)PADN * sizeof(int);

  (void)hipMemsetAsync(cursor, 0, ((size_t)N_NODES + 64) * sizeof(int), stream);  // cursor + bins
  wtrans_k<<<8, 256, 0, stream>>>(cW1, cW2, Wtb);
  build_k<<<(N_EDGES + 255) / 256, 256, 0, stream>>>(src, dst, cursor, slots);
  hist_k<<<PADN / 256, 256, 0, stream>>>(cursor, bins);
  scan_k<<<1, 64, 0, stream>>>(bins);
  scatter_k<<<PADN / 256, 256, 0, stream>>>(cursor, bins, perm);

  const int grid = PADN / 32;  // 3128 one-wave blocks
  // L1: emb -> t0; L2: t0 -> h; L3: h -> t0; L4: t0 -> h; pool reads h
  layer1_k<<<grid, 64, 0, stream>>>(x, node_emb, cursor, slots, perm,
                                    Wtb, Wtb + 16384, cb1, cb2, t0);
  layer_k<<<grid, 64, 0, stream>>>(t0, cursor, slots, perm,
                                   Wtb + 2 * 16384, Wtb + 3 * 16384,
                                   cb1 + HIDDEN, cb2 + HIDDEN, h);
  layer_k<<<grid, 64, 0, stream>>>(h, cursor, slots, perm,
                                   Wtb + 4 * 16384, Wtb + 5 * 16384,
                                   cb1 + 2 * HIDDEN, cb2 + 2 * HIDDEN, t0);
  layer_k<<<grid, 64, 0, stream>>>(t0, cursor, slots, perm,
                                   Wtb + 6 * 16384, Wtb + 7 * 16384,
                                   cb1 + 3 * HIDDEN, cb2 + 3 * HIDDEN, h);

  poolmlp_k<<<NUM_GRAPHS, 256, 0, stream>>>(h, batch, mW1, mb1, mW2, mb2, mW3, mb3, out);
}

// Round 13
// 361.090 us; speedup vs baseline: 1.0624x; 1.0624x over previous
//
#include <hip/hip_runtime.h>

#define N_NODES 100000
#define N_EDGES 625000
#define HIDDEN 128
#define NUM_GRAPHS 512
#define CAP 40       // max in-degree capacity; Poisson(6.25) => P(deg>40) ~ e-43
#define PADN 100096  // multiple of 256; 3128 gather-chunks of 32

typedef unsigned int uint;
typedef unsigned short ushort;
typedef short v8s __attribute__((ext_vector_type(8)));
typedef float v16f __attribute__((ext_vector_type(16)));

__device__ __forceinline__ float b2f_lo(uint u) { return __uint_as_float(u << 16); }
__device__ __forceinline__ float b2f_hi(uint u) { return __uint_as_float(u & 0xffff0000u); }
__device__ __forceinline__ uint f2b(float f) {  // RNE f32 -> bf16 bits
  uint u = __float_as_uint(f);
  return (u + 0x7fffu + ((u >> 16) & 1u)) >> 16;
}

// ---------------- weight quantize -> FRAGMENT-ORDERED bf16 ----------------
__global__ __launch_bounds__(256) void wtrans_k(const float* __restrict__ W1,
                                                const float* __restrict__ W2,
                                                ushort* __restrict__ Wt) {
  int mat = blockIdx.x;                       // 0..7 = layer*2 + which
  const float* W = ((mat & 1) ? W2 : W1) + (size_t)(mat >> 1) * 16384;
  ushort* o = Wt + (size_t)mat * 16384;
#pragma unroll
  for (int j = 0; j < 64; j++) {
    int idx = threadIdx.x + 256 * j;          // coalesced read W[k][n]
    int k = idx >> 7, n = idx & 127;
    int c = n >> 5, l31 = n & 31;
    int ks = k >> 4, khalf = (k >> 3) & 1, e = k & 7;
    o[(((c * 8 + ks) << 6) + (khalf << 5) + l31) * 8 + e] = (ushort)f2b(W[idx]);
  }
}

// ---------------- embed: h[n][:] = bf16(node_emb[x[n]][:]) ----------------
__global__ __launch_bounds__(256) void embed_k(const int* __restrict__ x,
                                               const float* __restrict__ emb,
                                               ushort* __restrict__ h) {
  int t = blockIdx.x * 256 + threadIdx.x;     // one 8-col chunk per thread
  int n = t >> 4;
  if (n >= N_NODES) return;
  int c = t & 15;
  const float4* e = (const float4*)(emb + (size_t)x[n] * HIDDEN + c * 8);
  float4 a = e[0], b = e[1];
  uint4 o;
  o.x = f2b(a.x) | (f2b(a.y) << 16);
  o.y = f2b(a.z) | (f2b(a.w) << 16);
  o.z = f2b(b.x) | (f2b(b.y) << 16);
  o.w = f2b(b.z) | (f2b(b.w) << 16);
  ((uint4*)h)[t] = o;
}

// ---------------- build dst-keyed adjacency (per call) ----------------
__global__ __launch_bounds__(256) void build_k(const int* __restrict__ src,
                                               const int* __restrict__ dst,
                                               int* __restrict__ cursor,
                                               int* __restrict__ slots) {
  int e = blockIdx.x * 256 + threadIdx.x;
  if (e >= N_EDGES) return;
  int d = dst[e];
  int p = atomicAdd(&cursor[d], 1);
  if (p < CAP) slots[(size_t)d * CAP + p] = src[e];
}

// ---------------- degree-grouped permutation, two-level (LDS-aggregated) ----------------
__global__ __launch_bounds__(256) void hist_k(const int* __restrict__ cursor,
                                              int* __restrict__ bins) {
  __shared__ int lb[CAP + 1];
  int tid = threadIdx.x;
  if (tid <= CAP) lb[tid] = 0;
  __syncthreads();
  int n = blockIdx.x * 256 + tid;
  if (n < N_NODES) {
    int d = cursor[n]; if (d > CAP) d = CAP;
    atomicAdd(&lb[d], 1);                     // LDS atomic: cheap
  }
  __syncthreads();
  if (tid <= CAP && lb[tid] > 0) atomicAdd(&bins[tid], lb[tid]);  // fire-and-forget
}

__global__ __launch_bounds__(64) void scan_k(int* __restrict__ bins) {
  int i = threadIdx.x;
  int c = (i <= CAP) ? bins[i] : 0;
  int incl = c;
#pragma unroll
  for (int off = 1; off < 64; off <<= 1) {
    int t = __shfl_up(incl, off, 64);
    if (i >= off) incl += t;
  }
  if (i <= CAP) bins[i] = incl - c;           // exclusive prefix
}

// LPT dispatch: perm REVERSED (descending degree) so deg-40 blocks launch first.
__global__ __launch_bounds__(256) void scatter_k(const int* __restrict__ cursor,
                                                 int* __restrict__ bins,
                                                 int* __restrict__ perm) {
  __shared__ int lb[CAP + 1];
  __shared__ int lbase[CAP + 1];
  int tid = threadIdx.x;
  if (tid <= CAP) lb[tid] = 0;
  __syncthreads();
  int n = blockIdx.x * 256 + tid;
  int d = 0, rank = 0;
  bool real = (n < N_NODES);
  if (real) {
    d = cursor[n]; if (d > CAP) d = CAP;
    rank = atomicAdd(&lb[d], 1);
  }
  __syncthreads();
  if (tid <= CAP) {
    int c = lb[tid];
    lbase[tid] = c > 0 ? atomicAdd(&bins[tid], c) : 0;
  }
  __syncthreads();
  if (real) perm[(N_NODES - 1) - (lbase[d] + rank)] = n;   // descending degree
  else if (n < PADN) perm[n] = 0;
}

// ================= shared GEMM tail (flip-GEMM1 + shfl z + GEMM2) =================
union U { uint4 u; v8s s; };

__device__ __forceinline__ void gemm_tail(const U afr[8],
                                          const ushort* __restrict__ W1f,
                                          const ushort* __restrict__ W2f,
                                          const float* __restrict__ b1,
                                          const float* __restrict__ b2,
                                          ushort* __restrict__ hout,
                                          int lane, int l31, int khalf,
                                          int tb, int prow) {
  // ---- GEMM1 (flipped): z^T = W1^T-as-A @ agg-as-B; lane = node row ----
  const uint4* W1v = (const uint4*)W1f;       // frag-ordered: slot*64 + lane
  v16f acc1[4] = {};
#pragma unroll
  for (int c = 0; c < 4; c++)
#pragma unroll
    for (int ks = 0; ks < 8; ks++) {
      U b; b.u = W1v[((c * 8 + ks) << 6) + lane];
      acc1[c] = __builtin_amdgcn_mfma_f32_32x32x16_bf16(b.s, afr[ks].s, acc1[c], 0, 0, 0);
    }

  // bias + relu + pack: lane holds z[r=l31][k'], k' = 32c + (reg&3) + 8*(reg>>2) + 4*khalf
  uint u[4][4][2];
#pragma unroll
  for (int c = 0; c < 4; c++)
#pragma unroll
    for (int b = 0; b < 4; b++)
#pragma unroll
      for (int ap = 0; ap < 2; ap++) {
        int r0 = 2 * ap + 4 * b, r1 = r0 + 1;
        float v0 = fmaxf(acc1[c][r0] + b1[c * 32 + 2 * ap + 8 * b + 4 * khalf], 0.f);
        float v1 = fmaxf(acc1[c][r1] + b1[c * 32 + 2 * ap + 1 + 8 * b + 4 * khalf], 0.f);
        u[c][b][ap] = f2b(v0) | (f2b(v1) << 16);
      }

  uint got[4][2][2];
#pragma unroll
  for (int c = 0; c < 4; c++)
#pragma unroll
    for (int bh = 0; bh < 2; bh++)
#pragma unroll
      for (int ap = 0; ap < 2; ap++) {
        uint send = khalf ? u[c][2 * bh][ap] : u[c][2 * bh + 1][ap];
        got[c][bh][ap] = __shfl_xor(send, 32, 64);
      }

  U az[8];
#pragma unroll
  for (int ks = 0; ks < 8; ks++) {
    uint o0 = khalf ? u[ks >> 1][2 * (ks & 1) + 1][0] : u[ks >> 1][2 * (ks & 1)][0];
    uint o1 = khalf ? u[ks >> 1][2 * (ks & 1) + 1][1] : u[ks >> 1][2 * (ks & 1)][1];
    uint g0 = got[ks >> 1][ks & 1][0];
    uint g1 = got[ks >> 1][ks & 1][1];
    az[ks].u.x = khalf ? g0 : o0;
    az[ks].u.y = khalf ? g1 : o1;
    az[ks].u.z = khalf ? o0 : g0;
    az[ks].u.w = khalf ? o1 : g1;
  }

  // ---- GEMM2 (normal): h_out = z @ W2 + b2 ----
  const uint4* W2v = (const uint4*)W2f;
  v16f acc2[4] = {};
#pragma unroll
  for (int c = 0; c < 4; c++)
#pragma unroll
    for (int ks = 0; ks < 8; ks++) {
      U b; b.u = W2v[((c * 8 + ks) << 6) + lane];
      acc2[c] = __builtin_amdgcn_mfma_f32_32x32x16_bf16(az[ks].s, b.s, acc2[c], 0, 0, 0);
    }

  int trow[16];
#pragma unroll
  for (int r = 0; r < 16; r++) {
    int m = (r & 3) + 8 * (r >> 2) + 4 * khalf;
    trow[r] = __shfl(prow, m, 64);
  }
  float bv2[4];
#pragma unroll
  for (int c = 0; c < 4; c++) bv2[c] = b2[c * 32 + l31];
#pragma unroll
  for (int c = 0; c < 4; c++) {
    int col = c * 32 + l31;
#pragma unroll
    for (int r = 0; r < 16; r++) {
      int m = (r & 3) + 8 * (r >> 2) + 4 * khalf;
      if (tb + m < N_NODES)
        hout[(size_t)trow[r] * HIDDEN + col] = (ushort)f2b(acc2[c][r] + bv2[c]);
    }
  }
}

// ---------------- fused layer: h_out = (relu((agg+h)@W1+b1))@W2 + b2 ----------------
// 2 waves per 32-row tile (block=128): wave0 sums self+even neighbors, wave1
// odd neighbors — halves each wave's serial L3-row chain. Partials combined
// via 16KB LDS float4 reduce (conflict-free); wave0 alone runs the GEMM tail.
// Depth-2 A/B pipeline per wave, sched_barrier pins loads above accumulates.
__device__ __forceinline__ void loadrow(uint4 dst[8], const uint4* __restrict__ rowp,
                                        int khalf) {
#pragma unroll
  for (int ks = 0; ks < 8; ks++) dst[ks] = rowp[khalf + 2 * ks];
}

__device__ __forceinline__ void accum8(const uint4 u[8], float acc[8][8]) {
#pragma unroll
  for (int ks = 0; ks < 8; ks++) {
    acc[ks][0] += b2f_lo(u[ks].x); acc[ks][1] += b2f_hi(u[ks].x);
    acc[ks][2] += b2f_lo(u[ks].y); acc[ks][3] += b2f_hi(u[ks].y);
    acc[ks][4] += b2f_lo(u[ks].z); acc[ks][5] += b2f_hi(u[ks].z);
    acc[ks][6] += b2f_lo(u[ks].w); acc[ks][7] += b2f_hi(u[ks].w);
  }
}

__global__ __launch_bounds__(128, 3) void layer_k(const ushort* __restrict__ hin,
                                                  const int* __restrict__ cursor,
                                                  const int* __restrict__ slots,
                                                  const int* __restrict__ perm,
                                                  const ushort* __restrict__ W1f,
                                                  const ushort* __restrict__ W2f,
                                                  const float* __restrict__ b1,
                                                  const float* __restrict__ b2,
                                                  ushort* __restrict__ hout) {
  __shared__ float4 red[1024];                // 16 KB: wave1's partial sums
  int tid = threadIdx.x;
  int lane = tid & 63;
  int wv = tid >> 6;                          // 0 or 1
  int l31 = lane & 31;
  int khalf = lane >> 5;
  int tb = blockIdx.x * 32;
  int prow = perm[tb + l31];
  bool valid = (tb + l31) < N_NODES;

  float acc[8][8];
#pragma unroll
  for (int ks = 0; ks < 8; ks++)
#pragma unroll
    for (int e = 0; e < 8; e++) acc[ks][e] = 0.f;

  const uint4* base = (const uint4*)hin;
  int deg = valid ? cursor[prow] : 0;
  if (deg > CAP) deg = CAP;
  const int* sl = slots + (size_t)prow * CAP;

  // wave0 list: self, n0, n2, ... (m = 1 + ceil(deg/2)); wave1: n1, n3, ... (m = deg/2)
  int m = wv ? (deg >> 1) : 1 + ((deg + 1) >> 1);
  uint4 A[8], B[8];
  if (m > 0) loadrow(A, base + (size_t)(wv ? sl[1] : prow) * 16, khalf);
  if (m > 1) loadrow(B, base + (size_t)(wv ? sl[3] : sl[0]) * 16, khalf);
  __builtin_amdgcn_sched_barrier(0);
  if (m > 0) accum8(A, acc);                  // item 0
  int i = 1;
  while (i + 1 < m) {
    int rA = wv ? sl[2 * (i + 1) + 1] : sl[2 * (i + 1) - 2];
    loadrow(A, base + (size_t)rA * 16, khalf);        // prefetch item i+2... into A
    __builtin_amdgcn_sched_barrier(0);
    accum8(B, acc);                           // item i
    if (i + 2 < m) {
      int rB = wv ? sl[2 * (i + 2) + 1] : sl[2 * (i + 2) - 2];
      loadrow(B, base + (size_t)rB * 16, khalf);
    }
    __builtin_amdgcn_sched_barrier(0);
    accum8(A, acc);                           // item i+1
    i += 2;
  }
  if (i < m) accum8(B, acc);                  // last odd item

  // combine: wave1 partials -> LDS; wave0 adds (order: wave0-sum then wave1-sum)
  if (wv == 1) {
#pragma unroll
    for (int ks = 0; ks < 8; ks++) {
      red[(ks * 2 + 0) * 64 + lane] = make_float4(acc[ks][0], acc[ks][1], acc[ks][2], acc[ks][3]);
      red[(ks * 2 + 1) * 64 + lane] = make_float4(acc[ks][4], acc[ks][5], acc[ks][6], acc[ks][7]);
    }
  }
  __syncthreads();
  if (wv == 1) return;
#pragma unroll
  for (int ks = 0; ks < 8; ks++) {
    float4 v0 = red[(ks * 2 + 0) * 64 + lane];
    float4 v1 = red[(ks * 2 + 1) * 64 + lane];
    acc[ks][0] += v0.x; acc[ks][1] += v0.y; acc[ks][2] += v0.z; acc[ks][3] += v0.w;
    acc[ks][4] += v1.x; acc[ks][5] += v1.y; acc[ks][6] += v1.z; acc[ks][7] += v1.w;
  }

  U afr[8];
#pragma unroll
  for (int ks = 0; ks < 8; ks++) {
    afr[ks].u.x = f2b(acc[ks][0]) | (f2b(acc[ks][1]) << 16);
    afr[ks].u.y = f2b(acc[ks][2]) | (f2b(acc[ks][3]) << 16);
    afr[ks].u.z = f2b(acc[ks][4]) | (f2b(acc[ks][5]) << 16);
    afr[ks].u.w = f2b(acc[ks][6]) | (f2b(acc[ks][7]) << 16);
  }

  gemm_tail(afr, W1f, W2f, b1, b2, hout, lane, l31, khalf, tb, prow);
}

// ---------------- fused pool+MLP: g = segsum(h); out = mlp(g) ----------------
__global__ __launch_bounds__(256) void poolmlp_k(const ushort* __restrict__ h,
                                                 const int* __restrict__ batch,
                                                 const float* __restrict__ W1, const float* __restrict__ b1,
                                                 const float* __restrict__ W2, const float* __restrict__ b2,
                                                 const float* __restrict__ W3, const float* __restrict__ b3,
                                                 float* __restrict__ out) {
  __shared__ int se[2];
  __shared__ float red[16][16][8];
  __shared__ float gl[128];
  __shared__ float r2[64];
  __shared__ float r3[32];
  int gi = blockIdx.x, tid = threadIdx.x;
  if (tid < 2) {
    int target = gi + tid;
    int lo = 0, hi = N_NODES;
    while (lo < hi) {
      int mid = (lo + hi) >> 1;
      if (batch[mid] < target) lo = mid + 1; else hi = mid;
    }
    se[tid] = lo;
  }
  __syncthreads();
  int start = se[0], end = se[1];
  int cg = tid & 15, rg = tid >> 4;
  float acc[8] = {0.f, 0.f, 0.f, 0.f, 0.f, 0.f, 0.f, 0.f};
  for (int r = start + rg; r < end; r += 16) {
    uint4 v = ((const uint4*)h)[r * 16 + cg];
    acc[0] += b2f_lo(v.x); acc[1] += b2f_hi(v.x);
    acc[2] += b2f_lo(v.y); acc[3] += b2f_hi(v.y);
    acc[4] += b2f_lo(v.z); acc[5] += b2f_hi(v.z);
    acc[6] += b2f_lo(v.w); acc[7] += b2f_hi(v.w);
  }
#pragma unroll
  for (int j = 0; j < 8; j++) red[rg][cg][j] = acc[j];
  __syncthreads();
  if (rg == 0) {
    float s[8];
#pragma unroll
    for (int j = 0; j < 8; j++) s[j] = red[0][cg][j];
#pragma unroll
    for (int i = 1; i < 16; i++)
#pragma unroll
      for (int j = 0; j < 8; j++) s[j] += red[i][cg][j];
#pragma unroll
    for (int j = 0; j < 8; j++) gl[cg * 8 + j] = s[j];
  }
  __syncthreads();
  if (tid < 64) {
    float s = b1[tid];
    for (int k = 0; k < 128; k++) s = fmaf(gl[k], W1[k * 64 + tid], s);
    r2[tid] = fmaxf(s, 0.f);
  }
  __syncthreads();
  if (tid < 32) {
    float s2 = b2[tid];
    for (int k = 0; k < 64; k++) s2 = fmaf(r2[k], W2[k * 32 + tid], s2);
    r3[tid] = fmaxf(s2, 0.f);
  }
  __syncthreads();
  if (tid < 64) {
    float pv = (tid < 32) ? r3[tid] * W3[tid] : 0.f;
#pragma unroll
    for (int off = 32; off > 0; off >>= 1) pv += __shfl_down(pv, off);
    if (tid == 0) out[gi] = pv + b3[0];
  }
}

extern "C" void kernel_launch(void* const* d_in, const int* in_sizes, int n_in,
                              void* d_out, int out_size, void* d_ws, size_t ws_size,
                              hipStream_t stream) {
  const int* x = (const int*)d_in[0];
  const int* src = (const int*)d_in[1];
  const int* dst = src + N_EDGES;
  const int* batch = (const int*)d_in[3];
  const float* node_emb = (const float*)d_in[4];
  const float* cW1 = (const float*)d_in[6];
  const float* cb1 = (const float*)d_in[7];
  const float* cW2 = (const float*)d_in[8];
  const float* cb2 = (const float*)d_in[9];
  const float* mW1 = (const float*)d_in[10];
  const float* mb1 = (const float*)d_in[11];
  const float* mW2 = (const float*)d_in[12];
  const float* mb2 = (const float*)d_in[13];
  const float* mW3 = (const float*)d_in[14];
  const float* mb3 = (const float*)d_in[15];
  float* out = (float*)d_out;

  char* p = (char*)d_ws;
  const size_t HB = (size_t)N_NODES * HIDDEN * sizeof(ushort);  // 25.6 MB
  ushort* h = (ushort*)p;      p += HB;
  ushort* t0 = (ushort*)p;     p += HB;
  ushort* Wtb = (ushort*)p;    p += (size_t)8 * 16384 * sizeof(ushort);
  int* cursor = (int*)p;       p += (size_t)N_NODES * sizeof(int);
  int* bins = (int*)p;         p += 64 * sizeof(int);
  int* slots = (int*)p;        p += (size_t)N_NODES * CAP * sizeof(int);
  int* perm = (int*)p;         p += (size_t)PADN * sizeof(int);

  (void)hipMemsetAsync(cursor, 0, ((size_t)N_NODES + 64) * sizeof(int), stream);  // cursor + bins
  wtrans_k<<<8, 256, 0, stream>>>(cW1, cW2, Wtb);
  embed_k<<<(N_NODES * 16 + 255) / 256, 256, 0, stream>>>(x, node_emb, h);
  build_k<<<(N_EDGES + 255) / 256, 256, 0, stream>>>(src, dst, cursor, slots);
  hist_k<<<PADN / 256, 256, 0, stream>>>(cursor, bins);
  scan_k<<<1, 64, 0, stream>>>(bins);
  scatter_k<<<PADN / 256, 256, 0, stream>>>(cursor, bins, perm);

  const int grid = PADN / 32;  // 3128 two-wave blocks
  ushort* bufs[2] = {h, t0};
  for (int l = 0; l < 4; l++) {
    layer_k<<<grid, 128, 0, stream>>>(bufs[l & 1], cursor, slots, perm,
                                      Wtb + (size_t)(2 * l) * 16384,
                                      Wtb + (size_t)(2 * l + 1) * 16384,
                                      cb1 + (size_t)l * HIDDEN,
                                      cb2 + (size_t)l * HIDDEN,
                                      bufs[(l & 1) ^ 1]);
  }
  // after 4 layers output is back in h (bufs[0])
  poolmlp_k<<<NUM_GRAPHS, 256, 0, stream>>>(h, batch, mW1, mb1, mW2, mb2, mW3, mb3, out);
}

// Round 14
// 340.633 us; speedup vs baseline: 1.1262x; 1.0601x over previous
//
#include <hip/hip_runtime.h>

#define N_NODES 100000
#define N_EDGES 625000
#define HIDDEN 128
#define NUM_GRAPHS 512
#define CAP 40       // max in-degree capacity; Poisson(6.25) => P(deg>40) ~ e-43
#define PADN 100096  // multiple of 256; 3128 gather-chunks of 32

#define BUILD_BLKS 2443   // ceil(625000/256)
#define EMBED_BLKS 6250   // N_NODES*16/256
#define WT_BLKS 64        // 8 mats x 8 chunks

typedef unsigned int uint;
typedef unsigned short ushort;
typedef short v8s __attribute__((ext_vector_type(8)));
typedef float v16f __attribute__((ext_vector_type(16)));

__device__ __forceinline__ float b2f_lo(uint u) { return __uint_as_float(u << 16); }
__device__ __forceinline__ float b2f_hi(uint u) { return __uint_as_float(u & 0xffff0000u); }
__device__ __forceinline__ uint f2b(float f) {  // RNE f32 -> bf16 bits
  uint u = __float_as_uint(f);
  return (u + 0x7fffu + ((u >> 16) & 1u)) >> 16;
}

// ---------------- fused prep: build adjacency + embed + weight-quantize ----------------
// Three independent jobs split by blockIdx range (one launch instead of three;
// wtrans previously ran on only 8 CUs ~15-20us as a straggler).
__global__ __launch_bounds__(256) void prep_k(const int* __restrict__ src,
                                              const int* __restrict__ dst,
                                              int* __restrict__ cursor,
                                              int* __restrict__ slots,
                                              const int* __restrict__ x,
                                              const float* __restrict__ emb,
                                              ushort* __restrict__ h,
                                              const float* __restrict__ W1,
                                              const float* __restrict__ W2,
                                              ushort* __restrict__ Wt) {
  int blk = blockIdx.x;
  int tid = threadIdx.x;
  if (blk < BUILD_BLKS) {
    int e = blk * 256 + tid;
    if (e < N_EDGES) {
      int d = dst[e];
      int p = atomicAdd(&cursor[d], 1);
      if (p < CAP) slots[(size_t)d * CAP + p] = src[e];
    }
  } else if (blk < BUILD_BLKS + EMBED_BLKS) {
    int t = (blk - BUILD_BLKS) * 256 + tid;   // one 8-col chunk per thread
    int n = t >> 4;
    if (n < N_NODES) {
      int c = t & 15;
      const float4* e4 = (const float4*)(emb + (size_t)x[n] * HIDDEN + c * 8);
      float4 a = e4[0], b = e4[1];
      uint4 o;
      o.x = f2b(a.x) | (f2b(a.y) << 16);
      o.y = f2b(a.z) | (f2b(a.w) << 16);
      o.z = f2b(b.x) | (f2b(b.y) << 16);
      o.w = f2b(b.z) | (f2b(b.w) << 16);
      ((uint4*)h)[t] = o;
    }
  } else {
    int wb = blk - BUILD_BLKS - EMBED_BLKS;   // 0..63
    int mat = wb >> 3, chunk = wb & 7;
    const float* W = ((mat & 1) ? W2 : W1) + (size_t)(mat >> 1) * 16384;
    ushort* o = Wt + (size_t)mat * 16384;
#pragma unroll
    for (int jj = 0; jj < 8; jj++) {
      int idx = chunk * 2048 + tid + 256 * jj;  // coalesced read W[k][n]
      int k = idx >> 7, n = idx & 127;
      int c = n >> 5, l31 = n & 31;
      int ks = k >> 4, khalf = (k >> 3) & 1, e = k & 7;
      // fragment-ordered: slot s=c*8+ks, lane=khalf*32+l31, elem e
      o[(((c * 8 + ks) << 6) + (khalf << 5) + l31) * 8 + e] = (ushort)f2b(W[idx]);
    }
  }
}

// ---------------- degree-grouped permutation, two-level (LDS-aggregated) ----------------
__global__ __launch_bounds__(256) void hist_k(const int* __restrict__ cursor,
                                              int* __restrict__ bins) {
  __shared__ int lb[CAP + 1];
  int tid = threadIdx.x;
  if (tid <= CAP) lb[tid] = 0;
  __syncthreads();
  int n = blockIdx.x * 256 + tid;
  if (n < N_NODES) {
    int d = cursor[n]; if (d > CAP) d = CAP;
    atomicAdd(&lb[d], 1);                     // LDS atomic: cheap
  }
  __syncthreads();
  if (tid <= CAP && lb[tid] > 0) atomicAdd(&bins[tid], lb[tid]);  // fire-and-forget
}

__global__ __launch_bounds__(64) void scan_k(int* __restrict__ bins) {
  int i = threadIdx.x;
  int c = (i <= CAP) ? bins[i] : 0;
  int incl = c;
#pragma unroll
  for (int off = 1; off < 64; off <<= 1) {
    int t = __shfl_up(incl, off, 64);
    if (i >= off) incl += t;
  }
  if (i <= CAP) bins[i] = incl - c;           // exclusive prefix
}

// LPT dispatch: perm REVERSED (descending degree) so deg-40 blocks launch first.
__global__ __launch_bounds__(256) void scatter_k(const int* __restrict__ cursor,
                                                 int* __restrict__ bins,
                                                 int* __restrict__ perm) {
  __shared__ int lb[CAP + 1];
  __shared__ int lbase[CAP + 1];
  int tid = threadIdx.x;
  if (tid <= CAP) lb[tid] = 0;
  __syncthreads();
  int n = blockIdx.x * 256 + tid;
  int d = 0, rank = 0;
  bool real = (n < N_NODES);
  if (real) {
    d = cursor[n]; if (d > CAP) d = CAP;
    rank = atomicAdd(&lb[d], 1);
  }
  __syncthreads();
  if (tid <= CAP) {
    int c = lb[tid];
    lbase[tid] = c > 0 ? atomicAdd(&bins[tid], c) : 0;
  }
  __syncthreads();
  if (real) perm[(N_NODES - 1) - (lbase[d] + rank)] = n;   // descending degree
  else if (n < PADN) perm[n] = 0;
}

// ---------------- fused layer: h_out = (relu((agg+h)@W1+b1))@W2 + b2 ----------------
// R10's proven config: ONE WAVE PER BLOCK (64 thr), 32 permuted rows, zero LDS,
// zero barriers; depth-2 A/B gather pipeline with sched_barrier(0) pinning
// loads above accumulates; W read as B-frags straight from global (L1/L2-hot).
union U { uint4 u; v8s s; };

__device__ __forceinline__ void loadrow(uint4 dst[8], const uint4* __restrict__ rowp,
                                        int khalf) {
#pragma unroll
  for (int ks = 0; ks < 8; ks++) dst[ks] = rowp[khalf + 2 * ks];
}

__device__ __forceinline__ void accum8(const uint4 u[8], float acc[8][8]) {
#pragma unroll
  for (int ks = 0; ks < 8; ks++) {
    acc[ks][0] += b2f_lo(u[ks].x); acc[ks][1] += b2f_hi(u[ks].x);
    acc[ks][2] += b2f_lo(u[ks].y); acc[ks][3] += b2f_hi(u[ks].y);
    acc[ks][4] += b2f_lo(u[ks].z); acc[ks][5] += b2f_hi(u[ks].z);
    acc[ks][6] += b2f_lo(u[ks].w); acc[ks][7] += b2f_hi(u[ks].w);
  }
}

__global__ __launch_bounds__(64, 3) void layer_k(const ushort* __restrict__ hin,
                                                 const int* __restrict__ cursor,
                                                 const int* __restrict__ slots,
                                                 const int* __restrict__ perm,
                                                 const ushort* __restrict__ W1f,
                                                 const ushort* __restrict__ W2f,
                                                 const float* __restrict__ b1,
                                                 const float* __restrict__ b2,
                                                 ushort* __restrict__ hout) {
  int lane = threadIdx.x;                     // 0..63
  int l31 = lane & 31;
  int khalf = lane >> 5;
  int tb = blockIdx.x * 32;                   // tile base in perm order
  int prow = perm[tb + l31];                  // true row this lane gathers
  bool valid = (tb + l31) < N_NODES;

  float acc[8][8];
#pragma unroll
  for (int ks = 0; ks < 8; ks++)
#pragma unroll
    for (int e = 0; e < 8; e++) acc[ks][e] = 0.f;

  const uint4* base = (const uint4*)hin;      // 16 uint4 per 128-col row
  uint4 A[8], B[8];
  loadrow(A, base + (size_t)prow * 16, khalf);          // self row -> A

  int deg = valid ? cursor[prow] : 0;
  if (deg > CAP) deg = CAP;
  const int* sl = slots + (size_t)prow * CAP;
  if (deg > 0) loadrow(B, base + (size_t)sl[0] * 16, khalf);   // nbr 0 -> B
  __builtin_amdgcn_sched_barrier(0);
  accum8(A, acc);                                       // self

  int j = 0;
  while (j + 2 <= deg) {
    loadrow(A, base + (size_t)sl[j + 1] * 16, khalf);   // nbr j+1 -> A
    __builtin_amdgcn_sched_barrier(0);
    accum8(B, acc);                                     // nbr j
    if (j + 2 < deg) loadrow(B, base + (size_t)sl[j + 2] * 16, khalf);  // nbr j+2 -> B
    __builtin_amdgcn_sched_barrier(0);
    accum8(A, acc);                                     // nbr j+1
    j += 2;
  }
  if (j < deg) accum8(B, acc);                          // last odd neighbor

  // round to bf16 A-frags (same rounding point as unfused t0 = bf16(agg+h))
  U afr[8];
#pragma unroll
  for (int ks = 0; ks < 8; ks++) {
    afr[ks].u.x = f2b(acc[ks][0]) | (f2b(acc[ks][1]) << 16);
    afr[ks].u.y = f2b(acc[ks][2]) | (f2b(acc[ks][3]) << 16);
    afr[ks].u.z = f2b(acc[ks][4]) | (f2b(acc[ks][5]) << 16);
    afr[ks].u.w = f2b(acc[ks][6]) | (f2b(acc[ks][7]) << 16);
  }

  // ---- GEMM1 (flipped): z^T = W1^T-as-A @ agg-as-B; lane = node row ----
  const uint4* W1v = (const uint4*)W1f;       // frag-ordered: slot*64 + lane
  v16f acc1[4] = {};
#pragma unroll
  for (int c = 0; c < 4; c++)
#pragma unroll
    for (int ks = 0; ks < 8; ks++) {
      U b; b.u = W1v[((c * 8 + ks) << 6) + lane];
      acc1[c] = __builtin_amdgcn_mfma_f32_32x32x16_bf16(b.s, afr[ks].s, acc1[c], 0, 0, 0);
    }

  // bias + relu + pack: lane holds z[r=l31][k'], k' = 32c + (reg&3) + 8*(reg>>2) + 4*khalf
  uint u[4][4][2];
#pragma unroll
  for (int c = 0; c < 4; c++)
#pragma unroll
    for (int b = 0; b < 4; b++)
#pragma unroll
      for (int ap = 0; ap < 2; ap++) {
        int r0 = 2 * ap + 4 * b, r1 = r0 + 1;
        float v0 = fmaxf(acc1[c][r0] + b1[c * 32 + 2 * ap + 8 * b + 4 * khalf], 0.f);
        float v1 = fmaxf(acc1[c][r1] + b1[c * 32 + 2 * ap + 1 + 8 * b + 4 * khalf], 0.f);
        u[c][b][ap] = f2b(v0) | (f2b(v1) << 16);
      }

  uint got[4][2][2];
#pragma unroll
  for (int c = 0; c < 4; c++)
#pragma unroll
    for (int bh = 0; bh < 2; bh++)
#pragma unroll
      for (int ap = 0; ap < 2; ap++) {
        uint send = khalf ? u[c][2 * bh][ap] : u[c][2 * bh + 1][ap];
        got[c][bh][ap] = __shfl_xor(send, 32, 64);
      }

  U az[8];
#pragma unroll
  for (int ks = 0; ks < 8; ks++) {
    uint o0 = khalf ? u[ks >> 1][2 * (ks & 1) + 1][0] : u[ks >> 1][2 * (ks & 1)][0];
    uint o1 = khalf ? u[ks >> 1][2 * (ks & 1) + 1][1] : u[ks >> 1][2 * (ks & 1)][1];
    uint g0 = got[ks >> 1][ks & 1][0];
    uint g1 = got[ks >> 1][ks & 1][1];
    az[ks].u.x = khalf ? g0 : o0;
    az[ks].u.y = khalf ? g1 : o1;
    az[ks].u.z = khalf ? o0 : g0;
    az[ks].u.w = khalf ? o1 : g1;
  }

  // ---- GEMM2 (normal): h_out = z @ W2 + b2 ----
  const uint4* W2v = (const uint4*)W2f;
  v16f acc2[4] = {};
#pragma unroll
  for (int c = 0; c < 4; c++)
#pragma unroll
    for (int ks = 0; ks < 8; ks++) {
      U b; b.u = W2v[((c * 8 + ks) << 6) + lane];
      acc2[c] = __builtin_amdgcn_mfma_f32_32x32x16_bf16(az[ks].s, b.s, acc2[c], 0, 0, 0);
    }

  int trow[16];
#pragma unroll
  for (int r = 0; r < 16; r++) {
    int m = (r & 3) + 8 * (r >> 2) + 4 * khalf;
    trow[r] = __shfl(prow, m, 64);
  }
  float bv2[4];
#pragma unroll
  for (int c = 0; c < 4; c++) bv2[c] = b2[c * 32 + l31];
#pragma unroll
  for (int c = 0; c < 4; c++) {
    int col = c * 32 + l31;
#pragma unroll
    for (int r = 0; r < 16; r++) {
      int m = (r & 3) + 8 * (r >> 2) + 4 * khalf;
      if (tb + m < N_NODES)
        hout[(size_t)trow[r] * HIDDEN + col] = (ushort)f2b(acc2[c][r] + bv2[c]);
    }
  }
}

// ---------------- fused pool+MLP: g = segsum(h); out = mlp(g) ----------------
__global__ __launch_bounds__(256) void poolmlp_k(const ushort* __restrict__ h,
                                                 const int* __restrict__ batch,
                                                 const float* __restrict__ W1, const float* __restrict__ b1,
                                                 const float* __restrict__ W2, const float* __restrict__ b2,
                                                 const float* __restrict__ W3, const float* __restrict__ b3,
                                                 float* __restrict__ out) {
  __shared__ int se[2];
  __shared__ float red[16][16][8];
  __shared__ float gl[128];
  __shared__ float r2[64];
  __shared__ float r3[32];
  int gi = blockIdx.x, tid = threadIdx.x;
  if (tid < 2) {
    int target = gi + tid;
    int lo = 0, hi = N_NODES;
    while (lo < hi) {
      int mid = (lo + hi) >> 1;
      if (batch[mid] < target) lo = mid + 1; else hi = mid;
    }
    se[tid] = lo;
  }
  __syncthreads();
  int start = se[0], end = se[1];
  int cg = tid & 15, rg = tid >> 4;
  float acc[8] = {0.f, 0.f, 0.f, 0.f, 0.f, 0.f, 0.f, 0.f};
  for (int r = start + rg; r < end; r += 16) {
    uint4 v = ((const uint4*)h)[r * 16 + cg];
    acc[0] += b2f_lo(v.x); acc[1] += b2f_hi(v.x);
    acc[2] += b2f_lo(v.y); acc[3] += b2f_hi(v.y);
    acc[4] += b2f_lo(v.z); acc[5] += b2f_hi(v.z);
    acc[6] += b2f_lo(v.w); acc[7] += b2f_hi(v.w);
  }
#pragma unroll
  for (int j = 0; j < 8; j++) red[rg][cg][j] = acc[j];
  __syncthreads();
  if (rg == 0) {
    float s[8];
#pragma unroll
    for (int j = 0; j < 8; j++) s[j] = red[0][cg][j];
#pragma unroll
    for (int i = 1; i < 16; i++)
#pragma unroll
      for (int j = 0; j < 8; j++) s[j] += red[i][cg][j];
#pragma unroll
    for (int j = 0; j < 8; j++) gl[cg * 8 + j] = s[j];
  }
  __syncthreads();
  if (tid < 64) {
    float s = b1[tid];
    for (int k = 0; k < 128; k++) s = fmaf(gl[k], W1[k * 64 + tid], s);
    r2[tid] = fmaxf(s, 0.f);
  }
  __syncthreads();
  if (tid < 32) {
    float s2 = b2[tid];
    for (int k = 0; k < 64; k++) s2 = fmaf(r2[k], W2[k * 32 + tid], s2);
    r3[tid] = fmaxf(s2, 0.f);
  }
  __syncthreads();
  if (tid < 64) {
    float pv = (tid < 32) ? r3[tid] * W3[tid] : 0.f;
#pragma unroll
    for (int off = 32; off > 0; off >>= 1) pv += __shfl_down(pv, off);
    if (tid == 0) out[gi] = pv + b3[0];
  }
}

extern "C" void kernel_launch(void* const* d_in, const int* in_sizes, int n_in,
                              void* d_out, int out_size, void* d_ws, size_t ws_size,
                              hipStream_t stream) {
  const int* x = (const int*)d_in[0];
  const int* src = (const int*)d_in[1];
  const int* dst = src + N_EDGES;
  const int* batch = (const int*)d_in[3];
  const float* node_emb = (const float*)d_in[4];
  const float* cW1 = (const float*)d_in[6];
  const float* cb1 = (const float*)d_in[7];
  const float* cW2 = (const float*)d_in[8];
  const float* cb2 = (const float*)d_in[9];
  const float* mW1 = (const float*)d_in[10];
  const float* mb1 = (const float*)d_in[11];
  const float* mW2 = (const float*)d_in[12];
  const float* mb2 = (const float*)d_in[13];
  const float* mW3 = (const float*)d_in[14];
  const float* mb3 = (const float*)d_in[15];
  float* out = (float*)d_out;

  char* p = (char*)d_ws;
  const size_t HB = (size_t)N_NODES * HIDDEN * sizeof(ushort);  // 25.6 MB
  ushort* h = (ushort*)p;      p += HB;
  ushort* t0 = (ushort*)p;     p += HB;
  ushort* Wtb = (ushort*)p;    p += (size_t)8 * 16384 * sizeof(ushort);
  int* cursor = (int*)p;       p += (size_t)N_NODES * sizeof(int);
  int* bins = (int*)p;         p += 64 * sizeof(int);
  int* slots = (int*)p;        p += (size_t)N_NODES * CAP * sizeof(int);
  int* perm = (int*)p;         p += (size_t)PADN * sizeof(int);

  (void)hipMemsetAsync(cursor, 0, ((size_t)N_NODES + 64) * sizeof(int), stream);  // cursor + bins
  prep_k<<<BUILD_BLKS + EMBED_BLKS + WT_BLKS, 256, 0, stream>>>(
      src, dst, cursor, slots, x, node_emb, h, cW1, cW2, Wtb);
  hist_k<<<PADN / 256, 256, 0, stream>>>(cursor, bins);
  scan_k<<<1, 64, 0, stream>>>(bins);
  scatter_k<<<PADN / 256, 256, 0, stream>>>(cursor, bins, perm);

  const int grid = PADN / 32;  // 3128 one-wave blocks
  ushort* bufs[2] = {h, t0};
  for (int l = 0; l < 4; l++) {
    layer_k<<<grid, 64, 0, stream>>>(bufs[l & 1], cursor, slots, perm,
                                     Wtb + (size_t)(2 * l) * 16384,
                                     Wtb + (size_t)(2 * l + 1) * 16384,
                                     cb1 + (size_t)l * HIDDEN,
                                     cb2 + (size_t)l * HIDDEN,
                                     bufs[(l & 1) ^ 1]);
  }
  // after 4 layers output is back in h (bufs[0])
  poolmlp_k<<<NUM_GRAPHS, 256, 0, stream>>>(h, batch, mW1, mb1, mW2, mb2, mW3, mb3, out);
}